// Round 6
// baseline (339.484 us; speedup 1.0000x reference)
//
#include <hip/hip_runtime.h>
#include <math.h>

// Problem shape (fixed by the reference):
//   q: [NB, DK] fp32, k: [NB, L, DK] fp32, v: [NB, L, DV] fp32
//   out0: [NB, DV] fp32, out1 (attn): [NB, L] fp32  (concatenated in d_out)
#define NB 1024
#define L  2048
#define DK 128
#define DV 128
#define CHUNK (L / 8)   // 256 rows owned by each wave

static constexpr float INV_TEMP = 0.088388347648318447f; // 1/sqrt(128)

// clang native vector type (HIP_vector_type float4 is a struct -> rejected by
// the nontemporal builtins).
typedef float f32x4 __attribute__((ext_vector_type(4)));

__device__ __forceinline__ f32x4 nt_load4(const float* p) {
    return __builtin_nontemporal_load(reinterpret_cast<const f32x4*>(p));
}
__device__ __forceinline__ void nt_store4(float* p, f32x4 x) {
    __builtin_nontemporal_store(x, reinterpret_cast<f32x4*>(p));
}

// Wave-private softmax kernel: each wave owns rows [256w, 256w+256) and runs
// QK^T -> in-wave softmax mid-step -> PV with NO block barrier in between
// (waves desynchronize; the block's memory pipe never idles). Normalization
// is deferred: PV uses p' = exp(s - lmax_w); everything is rescaled by
// exp(lmax_w - gmax)/gsum after one end barrier. attn output comes from the
// register copy of p' times a per-wave scalar (no extra exp passes).
__global__ __launch_bounds__(512, 8)
void mvsdpa_kernel(const float* __restrict__ q,
                   const float* __restrict__ k,
                   const float* __restrict__ v,
                   float* __restrict__ out,    // [NB, DV]
                   float* __restrict__ attn)   // [NB, L]
{
    const int b    = blockIdx.x;
    const int tid  = threadIdx.x;       // 0..511
    const int wave = tid >> 6;          // 0..7
    const int lane = tid & 63;
    const int half = lane >> 5;         // 0/1
    const int l32  = lane & 31;

    __shared__ float s_scores[L];          // raw scores, then p' = exp(s - lmax_w)
    __shared__ float s_red[16];            // [0..7]=wave lmax, [8..15]=wave lsum
    __shared__ float s_partial[16][DV];    // per-(wave,half) PV partials

    const float* qb = q + (size_t)b * DK;
    const float* kb = k + (size_t)b * (size_t)L * DK;
    const float* vb = v + (size_t)b * (size_t)L * DV;

    const f32x4 q4 = *reinterpret_cast<const f32x4*>(qb + l32 * 4);

    const int c0 = wave * CHUNK;        // own chunk [c0, c0+CHUNK)

    // ---- Phase 1: QK^T over own chunk ----
    // iter i: half h computes rows r0 = c0 + 4i + 2h and r1 = r0 + 1
    float lmax = -INFINITY;
    for (int i = 0; i < CHUNK / 4; ++i) {
        const int r0 = c0 + i * 4 + half * 2;
        const int r1 = r0 + 1;
        const f32x4 k40 = nt_load4(kb + (size_t)r0 * DK + l32 * 4);
        const f32x4 k41 = nt_load4(kb + (size_t)r1 * DK + l32 * 4);
        float d0 = q4.x * k40.x + q4.y * k40.y + q4.z * k40.z + q4.w * k40.w;
        float d1 = q4.x * k41.x + q4.y * k41.y + q4.z * k41.z + q4.w * k41.w;
        #pragma unroll
        for (int m = 1; m < 32; m <<= 1) {   // two independent reduce chains
            d0 += __shfl_xor(d0, m);
            d1 += __shfl_xor(d1, m);
        }
        d0 *= INV_TEMP;
        d1 *= INV_TEMP;
        lmax = fmaxf(lmax, fmaxf(d0, d1));
        if (l32 == 0) { s_scores[r0] = d0; s_scores[r1] = d1; }
    }
    lmax = fmaxf(lmax, __shfl_xor(lmax, 32));   // cross-half -> wave-chunk max

    // ---- v prefetch for the first 2 PV iters (in flight through mid-step) ----
    const int pr0 = c0 + half * 2;
    const f32x4 vp0 = nt_load4(vb + (size_t)(pr0)     * DV + l32 * 4);
    const f32x4 vp1 = nt_load4(vb + (size_t)(pr0 + 1) * DV + l32 * 4);
    const f32x4 vp2 = nt_load4(vb + (size_t)(pr0 + 4) * DV + l32 * 4);
    const f32x4 vp3 = nt_load4(vb + (size_t)(pr0 + 5) * DV + l32 * 4);

    // ---- in-wave softmax mid-step (no block barrier) ----
    // ensure this wave's cross-lane LDS score writes are complete
    asm volatile("s_waitcnt lgkmcnt(0)" ::: "memory");
    const f32x4 sv = *reinterpret_cast<const f32x4*>(&s_scores[c0 + lane * 4]);
    f32x4 pw;
    pw.x = __expf(sv.x - lmax);
    pw.y = __expf(sv.y - lmax);
    pw.z = __expf(sv.z - lmax);
    pw.w = __expf(sv.w - lmax);
    float lsum = pw.x + pw.y + pw.z + pw.w;
    #pragma unroll
    for (int m = 1; m < 64; m <<= 1) lsum += __shfl_xor(lsum, m);
    *reinterpret_cast<f32x4*>(&s_scores[c0 + lane * 4]) = pw;   // p' -> LDS for PV
    if (lane == 0) { s_red[wave] = lmax; s_red[8 + wave] = lsum; }
    asm volatile("s_waitcnt lgkmcnt(0)" ::: "memory");          // p' visible in-wave

    // ---- Phase 3: PV over own chunk with unnormalized p' ----
    f32x4 acc;
    {
        const float p0 = s_scores[pr0];
        const float p1 = s_scores[pr0 + 1];
        const float p2 = s_scores[pr0 + 4];
        const float p3 = s_scores[pr0 + 5];
        acc.x = p0 * vp0.x + p1 * vp1.x + p2 * vp2.x + p3 * vp3.x;
        acc.y = p0 * vp0.y + p1 * vp1.y + p2 * vp2.y + p3 * vp3.y;
        acc.z = p0 * vp0.z + p1 * vp1.z + p2 * vp2.z + p3 * vp3.z;
        acc.w = p0 * vp0.w + p1 * vp1.w + p2 * vp2.w + p3 * vp3.w;
    }
    for (int i = 2; i < CHUNK / 4; ++i) {
        const int r0 = c0 + i * 4 + half * 2;
        const int r1 = r0 + 1;
        const f32x4 v0 = nt_load4(vb + (size_t)r0 * DV + l32 * 4);
        const f32x4 v1 = nt_load4(vb + (size_t)r1 * DV + l32 * 4);
        const float p0 = s_scores[r0];   // broadcast within half-wave
        const float p1 = s_scores[r1];
        acc.x += p0 * v0.x + p1 * v1.x;
        acc.y += p0 * v0.y + p1 * v1.y;
        acc.z += p0 * v0.z + p1 * v1.z;
        acc.w += p0 * v0.w + p1 * v1.w;
    }

    __syncthreads();   // all waves' s_red published; partials ready to combine

    // ---- epilogue: global max/sum, attn, combine ----
    float gmax = s_red[0];
    #pragma unroll
    for (int w = 1; w < 8; ++w) gmax = fmaxf(gmax, s_red[w]);
    float gsum = 0.f;
    #pragma unroll
    for (int w = 0; w < 8; ++w) gsum += s_red[8 + w] * __expf(s_red[w] - gmax);
    const float factor = __expf(lmax - gmax) / gsum;   // per-wave rescale

    // attn for own chunk straight from the register copy of p' (coalesced)
    nt_store4(attn + (size_t)b * L + c0 + lane * 4, pw * factor);

    // combine per-(wave,half) PV partials
    acc *= factor;
    *reinterpret_cast<f32x4*>(&s_partial[wave * 2 + half][l32 * 4]) = acc;
    __syncthreads();
    if (tid < DV) {
        float s = 0.f;
        #pragma unroll
        for (int w = 0; w < 16; ++w) s += s_partial[w][tid];
        __builtin_nontemporal_store(s, out + (size_t)b * DV + tid);
    }
}

extern "C" void kernel_launch(void* const* d_in, const int* in_sizes, int n_in,
                              void* d_out, int out_size, void* d_ws, size_t ws_size,
                              hipStream_t stream) {
    const float* q = (const float*)d_in[0];
    const float* k = (const float*)d_in[1];
    const float* v = (const float*)d_in[2];
    float* out  = (float*)d_out;                   // [NB, DV]
    float* attn = (float*)d_out + (size_t)NB * DV; // [NB, L]
    mvsdpa_kernel<<<NB, 512, 0, stream>>>(q, k, v, out, attn);
}

// Round 7
// 322.103 us; speedup vs baseline: 1.0540x; 1.0540x over previous
//
#include <hip/hip_runtime.h>
#include <math.h>

// Problem shape (fixed by the reference):
//   q: [NB, DK] fp32, k: [NB, L, DK] fp32, v: [NB, L, DV] fp32
//   out0: [NB, DV] fp32, out1 (attn): [NB, L] fp32  (concatenated in d_out)
#define NB 1024
#define L  2048
#define DK 128
#define DV 128

static constexpr float INV_TEMP = 0.088388347648318447f; // 1/sqrt(128)

// clang native vector type (HIP_vector_type float4 is a struct -> rejected by
// the nontemporal builtins).
typedef float f32x4 __attribute__((ext_vector_type(4)));

__device__ __forceinline__ f32x4 nt_load4(const float* p) {
    return __builtin_nontemporal_load(reinterpret_cast<const f32x4*>(p));
}
__device__ __forceinline__ void nt_store4(float* p, f32x4 x) {
    __builtin_nontemporal_store(x, reinterpret_cast<f32x4*>(p));
}

// Round-5 skeleton (best measured: 318 us, 6.78 TB/s) + nontemporal stores.
//  P1: QK^T — block-cooperative contiguous k stream, 2 rows per (wave,half)
//      per iter, two independent float4-load + shfl-reduce chains
//  P2: softmax — per-wave max+expsum in one pass (single publish barrier),
//      4-deep cross-barrier v-prefetch keeps VMEM busy through this window
//  P3: PV — block-cooperative contiguous v stream, float4 loads, LDS combine
__global__ __launch_bounds__(512, 8)
void mvsdpa_kernel(const float* __restrict__ q,
                   const float* __restrict__ k,
                   const float* __restrict__ v,
                   float* __restrict__ out,    // [NB, DV]
                   float* __restrict__ attn)   // [NB, L]
{
    const int b    = blockIdx.x;
    const int tid  = threadIdx.x;       // 0..511
    const int wave = tid >> 6;          // 0..7
    const int lane = tid & 63;
    const int half = lane >> 5;         // 0/1
    const int l32  = lane & 31;

    __shared__ float s_scores[L];          // 8 KB: scores, then probabilities
    __shared__ float s_red[16];            // [0..7]=wave max, [8..15]=wave expsum
    __shared__ float s_partial[16][DV];    // 8 KB: per-(wave,half) PV partials

    const float* qb = q + (size_t)b * DK;
    const float* kb = k + (size_t)b * (size_t)L * DK;
    const float* vb = v + (size_t)b * (size_t)L * DV;

    const f32x4 q4 = *reinterpret_cast<const f32x4*>(qb + l32 * 4);

    // each (wave, half) pair owns rows 32*i + rbase and 32*i + rbase + 16
    const int rbase = wave * 2 + half;

    // ---- Phase 1: QK^T ----
    for (int i = 0; i < L / 32; ++i) {
        const int r0 = i * 32 + rbase;
        const int r1 = r0 + 16;
        const f32x4 k40 = nt_load4(kb + (size_t)r0 * DK + l32 * 4);
        const f32x4 k41 = nt_load4(kb + (size_t)r1 * DK + l32 * 4);
        float d0 = q4.x * k40.x + q4.y * k40.y + q4.z * k40.z + q4.w * k40.w;
        float d1 = q4.x * k41.x + q4.y * k41.y + q4.z * k41.z + q4.w * k41.w;
        #pragma unroll
        for (int m = 1; m < 32; m <<= 1) {   // two independent reduce chains (ILP)
            d0 += __shfl_xor(d0, m);
            d1 += __shfl_xor(d1, m);
        }
        if (l32 == 0) {
            s_scores[r0] = d0 * INV_TEMP;
            s_scores[r1] = d1 * INV_TEMP;
        }
    }

    // ---- cross-barrier v prefetch: 4 rows/lane stay in flight through softmax ----
    const f32x4 vp0 = nt_load4(vb + (size_t)(rbase)      * DV + l32 * 4);
    const f32x4 vp1 = nt_load4(vb + (size_t)(rbase + 16) * DV + l32 * 4);
    const f32x4 vp2 = nt_load4(vb + (size_t)(rbase + 32) * DV + l32 * 4);
    const f32x4 vp3 = nt_load4(vb + (size_t)(rbase + 48) * DV + l32 * 4);

    __syncthreads();

    // ---- Phase 2: softmax over L (single pass per wave: max then expsum) ----
    f32x4 sv = *reinterpret_cast<const f32x4*>(&s_scores[tid * 4]);
    float lmax = fmaxf(fmaxf(sv.x, sv.y), fmaxf(sv.z, sv.w));
    #pragma unroll
    for (int m = 1; m < 64; m <<= 1) lmax = fmaxf(lmax, __shfl_xor(lmax, m));

    f32x4 ev;
    ev.x = __expf(sv.x - lmax);
    ev.y = __expf(sv.y - lmax);
    ev.z = __expf(sv.z - lmax);
    ev.w = __expf(sv.w - lmax);
    float lsum = ev.x + ev.y + ev.z + ev.w;
    #pragma unroll
    for (int m = 1; m < 64; m <<= 1) lsum += __shfl_xor(lsum, m);

    if (lane == 0) { s_red[wave] = lmax; s_red[8 + wave] = lsum; }
    __syncthreads();

    float gmax = s_red[0];
    #pragma unroll
    for (int w = 1; w < 8; ++w) gmax = fmaxf(gmax, s_red[w]);
    float gsum = 0.f;
    #pragma unroll
    for (int w = 0; w < 8; ++w) gsum += s_red[8 + w] * __expf(s_red[w] - gmax);
    const float scale = __expf(lmax - gmax) / gsum;   // folds wave->global rescale

    sv.x = ev.x * scale; sv.y = ev.y * scale; sv.z = ev.z * scale; sv.w = ev.w * scale;
    *reinterpret_cast<f32x4*>(&s_scores[tid * 4]) = sv;              // p -> LDS
    nt_store4(attn + (size_t)b * L + tid * 4, sv);                   // coalesced nt
    __syncthreads();

    // ---- Phase 3: PV ----
    f32x4 acc;
    {   // i = 0,1 use the prefetched rows
        const float p0 = s_scores[rbase];
        const float p1 = s_scores[rbase + 16];
        const float p2 = s_scores[rbase + 32];
        const float p3 = s_scores[rbase + 48];
        acc.x = p0 * vp0.x + p1 * vp1.x + p2 * vp2.x + p3 * vp3.x;
        acc.y = p0 * vp0.y + p1 * vp1.y + p2 * vp2.y + p3 * vp3.y;
        acc.z = p0 * vp0.z + p1 * vp1.z + p2 * vp2.z + p3 * vp3.z;
        acc.w = p0 * vp0.w + p1 * vp1.w + p2 * vp2.w + p3 * vp3.w;
    }
    for (int i = 2; i < L / 32; ++i) {
        const int r0 = i * 32 + rbase;
        const int r1 = r0 + 16;
        const f32x4 v0 = nt_load4(vb + (size_t)r0 * DV + l32 * 4);
        const f32x4 v1 = nt_load4(vb + (size_t)r1 * DV + l32 * 4);
        const float p0 = s_scores[r0];    // broadcast within half-wave
        const float p1 = s_scores[r1];
        acc.x += p0 * v0.x + p1 * v1.x;
        acc.y += p0 * v0.y + p1 * v1.y;
        acc.z += p0 * v0.z + p1 * v1.z;
        acc.w += p0 * v0.w + p1 * v1.w;
    }
    *reinterpret_cast<f32x4*>(&s_partial[wave * 2 + half][l32 * 4]) = acc;
    __syncthreads();
    if (tid < DV) {
        float s = 0.f;
        #pragma unroll
        for (int w = 0; w < 16; ++w) s += s_partial[w][tid];
        __builtin_nontemporal_store(s, out + (size_t)b * DV + tid);
    }
}

extern "C" void kernel_launch(void* const* d_in, const int* in_sizes, int n_in,
                              void* d_out, int out_size, void* d_ws, size_t ws_size,
                              hipStream_t stream) {
    const float* q = (const float*)d_in[0];
    const float* k = (const float*)d_in[1];
    const float* v = (const float*)d_in[2];
    float* out  = (float*)d_out;                   // [NB, DV]
    float* attn = (float*)d_out + (size_t)NB * DV; // [NB, L]
    mvsdpa_kernel<<<NB, 512, 0, stream>>>(q, k, v, out, attn);
}